// Round 6
// baseline (123.658 us; speedup 1.0000x reference)
//
#include <hip/hip_runtime.h>
#include <hip/hip_bf16.h>
#include <stdint.h>

// Linear4bit R6: chunk-major packed fp4 pre-pass (unchanged) + MX-fp4 GEMM
// with m201-style schedule: 2 phases per K-tile (8-MFMA clusters), G-loads
// spread 2/wave/phase, raw barriers, setprio, NO sched_barrier pins,
// vmcnt(0)+barrier once per tile. Swizzle: bn fast axis.

#define M_DIM 8192
#define N_DIM 4096
#define K_MAIN 4096
#define K_TOT 4224
#define NCHUNK 132
#define NT 33

#define XP_OFF   ((size_t)0)
#define WP_OFF   (XP_OFF + (size_t)NCHUNK * M_DIM * 16)
#define SXH_OFF  (WP_OFF + (size_t)NCHUNK * N_DIM * 16)
#define SWH_OFF  (SXH_OFF + (size_t)NT * 2 * M_DIM * 2)
#define WS_NEED  (SWH_OFF + (size_t)NT * 2 * N_DIM * 2)

typedef __attribute__((ext_vector_type(4))) float f32x4;
typedef __attribute__((ext_vector_type(16))) float f32x16;
typedef __attribute__((ext_vector_type(8))) short short8;
typedef __attribute__((ext_vector_type(8))) _Float16 half8;
typedef __attribute__((ext_vector_type(4))) int i32x4;
typedef __attribute__((ext_vector_type(8))) int i32x8;

#define SBAR() asm volatile("s_barrier" ::: "memory")

#define PXP_N (NCHUNK * M_DIM)
#define PWP_N (NCHUNK * N_DIM)
#define TSX_N (NT * 2 * M_DIM / 2)
#define TSW_N (NT * 2 * N_DIM / 2)
#define PACK_TOTAL (PXP_N + PWP_N + TSX_N + TSW_N)

__device__ inline unsigned pack4(i32x4 q) {
    return (q.x & 255) | ((q.y & 255) << 8) | ((q.z & 255) << 16) |
           ((unsigned)(q.w & 255) << 24);
}

__global__ __launch_bounds__(256)
void pack_kernel(const int* __restrict__ xq, const int* __restrict__ sx,
                 const int* __restrict__ w, const int* __restrict__ sfw,
                 const int* __restrict__ lrw, const int* __restrict__ sflr,
                 uint8_t* __restrict__ ws) {
    int t = blockIdx.x * 256 + threadIdx.x;
    if (t < PXP_N) {
        const int g = t >> 13;
        const int m = t & 8191;
        const int gs = (g < 128) ? g : (g - 128);
        const int* src = xq + (size_t)m * 2048 + gs * 16;
        i32x4 o;
        o.x = (int)pack4(*(const i32x4*)(src + 0));
        o.y = (int)pack4(*(const i32x4*)(src + 4));
        o.z = (int)pack4(*(const i32x4*)(src + 8));
        o.w = (int)pack4(*(const i32x4*)(src + 12));
        *(i32x4*)(ws + XP_OFF + ((size_t)g * M_DIM + m) * 16) = o;
    } else if (t < PXP_N + PWP_N) {
        const int i = t - PXP_N;
        const int g = i >> 12;
        const int n = i & 4095;
        const int* src = (g < 128) ? (w + (size_t)n * 2048 + g * 16)
                                   : (lrw + (size_t)n * 64 + (g - 128) * 16);
        i32x4 o;
        o.x = (int)pack4(*(const i32x4*)(src + 0));
        o.y = (int)pack4(*(const i32x4*)(src + 4));
        o.z = (int)pack4(*(const i32x4*)(src + 8));
        o.w = (int)pack4(*(const i32x4*)(src + 12));
        *(i32x4*)(ws + WP_OFF + ((size_t)g * N_DIM + n) * 16) = o;
    } else if (t < PXP_N + PWP_N + TSX_N) {
        int i = t - PXP_N - PWP_N;
        int plane = i >> 12;
        int kt = plane >> 1, h = plane & 1;
        int r2 = (i & 4095) << 1;
        int g0 = kt * 4 + h, g2 = g0 + 2;
        int s0 = (g0 < 128) ? g0 : g0 - 128;
        int s2 = (g2 < 128) ? g2 : g2 - 128;
        unsigned b0 = sx[(size_t)r2 * 128 + s0] & 255;
        unsigned b1 = sx[(size_t)r2 * 128 + s2] & 255;
        unsigned b2 = sx[(size_t)(r2 + 1) * 128 + s0] & 255;
        unsigned b3 = sx[(size_t)(r2 + 1) * 128 + s2] & 255;
        *(unsigned*)(ws + SXH_OFF + (size_t)i * 4) = b0 | (b1 << 8) | (b2 << 16) | (b3 << 24);
    } else if (t < PACK_TOTAL) {
        int i = t - PXP_N - PWP_N - TSX_N;
        int plane = i >> 11;
        int kt = plane >> 1, h = plane & 1;
        int r2 = (i & 2047) << 1;
        int g0 = kt * 4 + h, g2 = g0 + 2;
        unsigned b0, b1, b2, b3;
        if (g0 < 128) { b0 = sfw[(size_t)r2 * 128 + g0] & 255; b2 = sfw[(size_t)(r2 + 1) * 128 + g0] & 255; }
        else          { b0 = sflr[(size_t)r2 * 4 + (g0 - 128)] & 255; b2 = sflr[(size_t)(r2 + 1) * 4 + (g0 - 128)] & 255; }
        if (g2 < 128) { b1 = sfw[(size_t)r2 * 128 + g2] & 255; b3 = sfw[(size_t)(r2 + 1) * 128 + g2] & 255; }
        else          { b1 = sflr[(size_t)r2 * 4 + (g2 - 128)] & 255; b3 = sflr[(size_t)(r2 + 1) * 4 + (g2 - 128)] & 255; }
        *(unsigned*)(ws + SWH_OFF + (size_t)i * 4) = b0 | (b1 << 8) | (b2 << 16) | (b3 << 24);
    }
}

__device__ inline void gload_lds16(const void* g, void* l) {
    __builtin_amdgcn_global_load_lds(
        (const __attribute__((address_space(1))) unsigned int*)g,
        (__attribute__((address_space(3))) unsigned int*)l, 16, 0, 0);
}

// Stage half a tile: half=0 -> rows 0..127, half=1 -> rows 128..255.
// Wave wid<4 handles A chunk wid; wid>=4 handles B chunk wid-4. 2 glds/wave.
__device__ inline void stage_half(const uint8_t* __restrict__ xp,
                                  const uint8_t* __restrict__ wp,
                                  int bm, int bn, int tt, int half,
                                  uint8_t (*As)[256][16], uint8_t (*Bs)[256][16],
                                  int wid, int lane) {
    const int c = wid & 3;
    const int q0 = half * 2;
    if (wid < 4) {
        const uint8_t* g = xp + ((size_t)(tt * 4 + c) * M_DIM + bm + lane) * 16;
        gload_lds16(g + (size_t)q0 * 64 * 16, &As[c][q0 * 64][0]);
        gload_lds16(g + (size_t)(q0 + 1) * 64 * 16, &As[c][(q0 + 1) * 64][0]);
    } else {
        const uint8_t* g = wp + ((size_t)(tt * 4 + c) * N_DIM + bn + lane) * 16;
        gload_lds16(g + (size_t)q0 * 64 * 16, &Bs[c][q0 * 64][0]);
        gload_lds16(g + (size_t)(q0 + 1) * 64 * 16, &Bs[c][(q0 + 1) * 64][0]);
    }
}

__device__ inline void load_scales(const uint8_t* __restrict__ sxH,
                                   const uint8_t* __restrict__ swH,
                                   int bm, int bn, int tt, int* sa, int* sb,
                                   int wr, int wc, int lane) {
    const int h = lane >> 5, r = lane & 31;
    const uint8_t* px = sxH + (size_t)((tt * 2 + h) * M_DIM + bm + wr * 128 + r) * 2;
#pragma unroll
    for (int mi = 0; mi < 4; ++mi) sa[mi] = *(const unsigned short*)(px + mi * 64);
    const uint8_t* pw = swH + (size_t)((tt * 2 + h) * N_DIM + bn + wc * 64 + r) * 2;
#pragma unroll
    for (int ni = 0; ni < 2; ++ni) sb[ni] = *(const unsigned short*)(pw + ni * 64);
}

// 8-MFMA cluster for one kk: mi=0..3 x ni=0..1.
template <int KK>
__device__ inline void mfma_oct(const i32x4* af, const i32x4* bf,
                                f32x16 (&acc)[4][2], const int* sa, const int* sb) {
    i32x8 a[4], b[2];
#pragma unroll
    for (int mi = 0; mi < 4; ++mi)
        a[mi] = i32x8{af[mi].x, af[mi].y, af[mi].z, af[mi].w, 0, 0, 0, 0};
#pragma unroll
    for (int ni = 0; ni < 2; ++ni)
        b[ni] = i32x8{bf[ni].x, bf[ni].y, bf[ni].z, bf[ni].w, 0, 0, 0, 0};
#pragma unroll
    for (int mi = 0; mi < 4; ++mi)
#pragma unroll
        for (int ni = 0; ni < 2; ++ni)
            acc[mi][ni] = __builtin_amdgcn_mfma_scale_f32_32x32x64_f8f6f4(
                a[mi], b[ni], acc[mi][ni], 4, 4, KK, sa[mi], KK, sb[ni]);
}

__global__ __launch_bounds__(512, 2)
void l4b_mx5(const uint8_t* __restrict__ xp, const uint8_t* __restrict__ wp,
             const uint8_t* __restrict__ sxH, const uint8_t* __restrict__ swH,
             float* __restrict__ out) {
    __shared__ __align__(16) uint8_t As[2][4][256][16];
    __shared__ __align__(16) uint8_t Bs[2][4][256][16];

    const int tid = threadIdx.x;
    const int lane = tid & 63;
    const int wid = tid >> 6;
    const int wr = wid >> 2;   // 0..1
    const int wc = wid & 3;    // 0..3

    // XCD-aware bijective swizzle, bn fast axis (A-panels L2-resident per XCD)
    const int bid = blockIdx.x;
    const int wgid = (bid & 7) * 64 + (bid >> 3);
    const int bn = (wgid & 15) * 256;
    const int bm = (wgid >> 4) * 256;

    const int h = lane >> 5, r = lane & 31;

    f32x16 acc[4][2] = {};
    int sa[4], sb[2], san[4], sbn[2];

    stage_half(xp, wp, bm, bn, 0, 0, As[0], Bs[0], wid, lane);
    stage_half(xp, wp, bm, bn, 0, 1, As[0], Bs[0], wid, lane);
    load_scales(sxH, swH, bm, bn, 0, sa, sb, wr, wc, lane);
    asm volatile("s_waitcnt vmcnt(0)" ::: "memory");
    SBAR();

    int cur = 0;
    for (int t = 0; t < NT; ++t) {
        const int nxt = cur ^ 1;
        const bool pre = (t + 1 < NT);
        i32x4 af[4], bf[2];

        // ===== phase 0: kk=0 =====
#pragma unroll
        for (int mi = 0; mi < 4; ++mi)
            af[mi] = *(const i32x4*)&As[cur][h][wr * 128 + mi * 32 + r][0];
#pragma unroll
        for (int ni = 0; ni < 2; ++ni)
            bf[ni] = *(const i32x4*)&Bs[cur][h][wc * 64 + ni * 32 + r][0];
        if (pre) {
            stage_half(xp, wp, bm, bn, t + 1, 0, As[nxt], Bs[nxt], wid, lane);
            load_scales(sxH, swH, bm, bn, t + 1, san, sbn, wr, wc, lane);
        }
        SBAR();
        __builtin_amdgcn_s_setprio(1);
        mfma_oct<0>(af, bf, acc, sa, sb);
        __builtin_amdgcn_s_setprio(0);
        SBAR();

        // ===== phase 1: kk=1 =====
#pragma unroll
        for (int mi = 0; mi < 4; ++mi)
            af[mi] = *(const i32x4*)&As[cur][2 + h][wr * 128 + mi * 32 + r][0];
#pragma unroll
        for (int ni = 0; ni < 2; ++ni)
            bf[ni] = *(const i32x4*)&Bs[cur][2 + h][wc * 64 + ni * 32 + r][0];
        if (pre)
            stage_half(xp, wp, bm, bn, t + 1, 1, As[nxt], Bs[nxt], wid, lane);
        SBAR();
        __builtin_amdgcn_s_setprio(1);
        mfma_oct<1>(af, bf, acc, sa, sb);
        __builtin_amdgcn_s_setprio(0);
        asm volatile("s_waitcnt vmcnt(0)" ::: "memory");
        SBAR();

        cur = nxt;
#pragma unroll
        for (int i = 0; i < 4; ++i) sa[i] = san[i];
        sb[0] = sbn[0]; sb[1] = sbn[1];
    }

    // epilogue: 32x32 C/D layout col=lane&31, row=(reg&3)+8*(reg>>2)+4*(lane>>5)
#pragma unroll
    for (int mi = 0; mi < 4; ++mi)
#pragma unroll
        for (int ni = 0; ni < 2; ++ni) {
            const int col = bn + wc * 64 + ni * 32 + (lane & 31);
            const int rb = bm + wr * 128 + mi * 32 + 4 * (lane >> 5);
#pragma unroll
            for (int reg = 0; reg < 16; ++reg) {
                const int row = rb + (reg & 3) + 8 * (reg >> 2);
                out[(size_t)row * N_DIM + col] = acc[mi][ni][reg];
            }
        }
}

// ======================= fallback (fused f16 dequant GEMM) =======================
__device__ inline short8 dequant8_f16(i32x4 q, int sf) {
    unsigned b = (unsigned)q.x | ((unsigned)q.y << 8) |
                 ((unsigned)q.z << 16) | ((unsigned)q.w << 24);
    unsigned me = b & 0x07070707u;
    unsigned mo = (b >> 4) & 0x07070707u;
    const unsigned TLO = 0x3E3C3800u;
    const unsigned THI = 0x46444240u;
    unsigned He = __builtin_amdgcn_perm(THI, TLO, me);
    unsigned Ho = __builtin_amdgcn_perm(THI, TLO, mo);
    He |= (b & 0x08080808u) << 4;
    Ho |= (b & 0x80808080u);
    unsigned d0 = __builtin_amdgcn_perm(He, 0u, 0x05010400u);
    unsigned d1 = __builtin_amdgcn_perm(He, 0u, 0x07000600u);
    unsigned d2 = __builtin_amdgcn_perm(Ho, 0u, 0x05010400u);
    unsigned d3 = __builtin_amdgcn_perm(Ho, 0u, 0x07000600u);
    i32x4 di; di.x = (int)d0; di.y = (int)d1; di.z = (int)d2; di.w = (int)d3;
    half8 hh = __builtin_bit_cast(half8, di);
    unsigned short se = (unsigned short)((sf - 112) << 10);
    int srep = (int)((unsigned)se | ((unsigned)se << 16));
    i32x4 si; si.x = srep; si.y = srep; si.z = srep; si.w = srep;
    hh = hh * __builtin_bit_cast(half8, si);
    return __builtin_bit_cast(short8, hh);
}

__global__ __launch_bounds__(256)
void l4b_fused(const int* __restrict__ x_q, const int* __restrict__ scales_x,
               const int* __restrict__ weight, const int* __restrict__ SF_w,
               const int* __restrict__ lrw, const int* __restrict__ SF_lr,
               float* __restrict__ out) {
    __shared__ short As[128 * 64];
    __shared__ short Bs[128 * 64];
    const int tid = threadIdx.x;
    const int lane = tid & 63;
    const int wid = tid >> 6;
    const int wr = wid >> 1, wc = wid & 1;
    const int bm = blockIdx.y * 128, bn = blockIdx.x * 128;
    const int srow = tid >> 3;
    const int scol = (tid & 7) * 8;
    f32x4 acc[4][4] = {};
    for (int kt = 0; kt < K_TOT / 64; ++kt) {
        const int k0 = kt * 64;
        __syncthreads();
#pragma unroll
        for (int it = 0; it < 4; ++it) {
            const int row = it * 32 + srow;
            const int k = k0 + scol;
            const int ksrc = (k < K_MAIN) ? k : (k - K_MAIN);
            i32x4 q = *(const i32x4*)(x_q + (size_t)(bm + row) * 2048 + (ksrc >> 1));
            int sf = scales_x[(size_t)(bm + row) * 128 + (ksrc >> 5)];
            short8 v = dequant8_f16(q, sf);
            unsigned a = (unsigned)(row * 128 + scol * 2) ^ (unsigned)((row & 7) << 4);
            *(short8*)((char*)As + a) = v;
        }
#pragma unroll
        for (int it = 0; it < 4; ++it) {
            const int row = it * 32 + srow;
            const int k = k0 + scol;
            i32x4 q; int sf;
            if (k < K_MAIN) {
                q = *(const i32x4*)(weight + (size_t)(bn + row) * 2048 + (k >> 1));
                sf = SF_w[(size_t)(bn + row) * 128 + (k >> 5)];
            } else {
                q = *(const i32x4*)(lrw + (size_t)(bn + row) * 64 + ((k - K_MAIN) >> 1));
                sf = SF_lr[(size_t)(bn + row) * 4 + ((k - K_MAIN) >> 5)];
            }
            short8 v = dequant8_f16(q, sf);
            unsigned a = (unsigned)(row * 128 + scol * 2) ^ (unsigned)((row & 7) << 4);
            *(short8*)((char*)Bs + a) = v;
        }
        __syncthreads();
#pragma unroll
        for (int ks = 0; ks < 2; ++ks) {
            const int koff = ks * 32 + (lane >> 4) * 8;
            short8 af[4], bfr[4];
#pragma unroll
            for (int mi = 0; mi < 4; ++mi) {
                const int row = wr * 64 + mi * 16 + (lane & 15);
                unsigned a = (unsigned)(row * 128 + koff * 2) ^ (unsigned)((row & 7) << 4);
                af[mi] = *(const short8*)((const char*)As + a);
            }
#pragma unroll
            for (int ni = 0; ni < 4; ++ni) {
                const int row = wc * 64 + ni * 16 + (lane & 15);
                unsigned a = (unsigned)(row * 128 + koff * 2) ^ (unsigned)((row & 7) << 4);
                bfr[ni] = *(const short8*)((const char*)Bs + a);
            }
#pragma unroll
            for (int mi = 0; mi < 4; ++mi)
#pragma unroll
                for (int ni = 0; ni < 4; ++ni)
                    acc[mi][ni] = __builtin_amdgcn_mfma_f32_16x16x32_f16(
                        __builtin_bit_cast(half8, af[mi]),
                        __builtin_bit_cast(half8, bfr[ni]),
                        acc[mi][ni], 0, 0, 0);
        }
    }
#pragma unroll
    for (int mi = 0; mi < 4; ++mi)
#pragma unroll
        for (int ni = 0; ni < 4; ++ni) {
            const int col = bn + wc * 64 + ni * 16 + (lane & 15);
            const int row0 = bm + wr * 64 + mi * 16 + (lane >> 4) * 4;
#pragma unroll
            for (int r2 = 0; r2 < 4; ++r2)
                out[(size_t)(row0 + r2) * N_DIM + col] = acc[mi][ni][r2];
        }
}

extern "C" void kernel_launch(void* const* d_in, const int* in_sizes, int n_in,
                              void* d_out, int out_size, void* d_ws, size_t ws_size,
                              hipStream_t stream) {
    const int* x_q  = (const int*)d_in[0];
    const int* sx   = (const int*)d_in[1];
    const int* w    = (const int*)d_in[2];
    const int* sfw  = (const int*)d_in[3];
    const int* lrw  = (const int*)d_in[4];
    const int* sflr = (const int*)d_in[5];
    float* out = (float*)d_out;

    if (ws_size >= WS_NEED) {
        uint8_t* ws = (uint8_t*)d_ws;
        pack_kernel<<<(PACK_TOTAL + 255) / 256, 256, 0, stream>>>(x_q, sx, w, sfw, lrw, sflr, ws);
        l4b_mx5<<<(M_DIM / 256) * (N_DIM / 256), 512, 0, stream>>>(
            ws + XP_OFF, ws + WP_OFF, ws + SXH_OFF, ws + SWH_OFF, out);
    } else {
        dim3 grid(N_DIM / 128, M_DIM / 128);
        l4b_fused<<<grid, dim3(256), 0, stream>>>(x_q, sx, w, sfw, lrw, sflr, out);
    }
}

// Round 7
// 120.302 us; speedup vs baseline: 1.0279x; 1.0279x over previous
//
#include <hip/hip_runtime.h>
#include <hip/hip_bf16.h>
#include <stdint.h>

// Linear4bit R7: chunk-major packed fp4 pre-pass (unchanged) + MX-fp4 GEMM
// with T3 minimum-2-phase schedule: per K-tile {stage t+1; 12 ds_read (imm
// offsets); 16-MFMA cluster w/ setprio; vmcnt(0); ONE s_barrier}. Loop-carried
// pointers (no per-tile address recompute). 256x256 tile, 8 waves, BK=128.

#define M_DIM 8192
#define N_DIM 4096
#define K_MAIN 4096
#define K_TOT 4224
#define NCHUNK 132
#define NT 33

#define XP_OFF   ((size_t)0)
#define WP_OFF   (XP_OFF + (size_t)NCHUNK * M_DIM * 16)
#define SXH_OFF  (WP_OFF + (size_t)NCHUNK * N_DIM * 16)
#define SWH_OFF  (SXH_OFF + (size_t)NT * 2 * M_DIM * 2)
#define WS_NEED  (SWH_OFF + (size_t)NT * 2 * N_DIM * 2)

typedef __attribute__((ext_vector_type(4))) float f32x4;
typedef __attribute__((ext_vector_type(16))) float f32x16;
typedef __attribute__((ext_vector_type(8))) short short8;
typedef __attribute__((ext_vector_type(8))) _Float16 half8;
typedef __attribute__((ext_vector_type(4))) int i32x4;
typedef __attribute__((ext_vector_type(8))) int i32x8;

#define SBAR() asm volatile("s_barrier" ::: "memory")

#define PXP_N (NCHUNK * M_DIM)
#define PWP_N (NCHUNK * N_DIM)
#define TSX_N (NT * 2 * M_DIM / 2)
#define TSW_N (NT * 2 * N_DIM / 2)
#define PACK_TOTAL (PXP_N + PWP_N + TSX_N + TSW_N)

__device__ inline unsigned pack4(i32x4 q) {
    return (q.x & 255) | ((q.y & 255) << 8) | ((q.z & 255) << 16) |
           ((unsigned)(q.w & 255) << 24);
}

__global__ __launch_bounds__(256)
void pack_kernel(const int* __restrict__ xq, const int* __restrict__ sx,
                 const int* __restrict__ w, const int* __restrict__ sfw,
                 const int* __restrict__ lrw, const int* __restrict__ sflr,
                 uint8_t* __restrict__ ws) {
    int t = blockIdx.x * 256 + threadIdx.x;
    if (t < PXP_N) {
        const int g = t >> 13;
        const int m = t & 8191;
        const int gs = (g < 128) ? g : (g - 128);
        const int* src = xq + (size_t)m * 2048 + gs * 16;
        i32x4 o;
        o.x = (int)pack4(*(const i32x4*)(src + 0));
        o.y = (int)pack4(*(const i32x4*)(src + 4));
        o.z = (int)pack4(*(const i32x4*)(src + 8));
        o.w = (int)pack4(*(const i32x4*)(src + 12));
        *(i32x4*)(ws + XP_OFF + ((size_t)g * M_DIM + m) * 16) = o;
    } else if (t < PXP_N + PWP_N) {
        const int i = t - PXP_N;
        const int g = i >> 12;
        const int n = i & 4095;
        const int* src = (g < 128) ? (w + (size_t)n * 2048 + g * 16)
                                   : (lrw + (size_t)n * 64 + (g - 128) * 16);
        i32x4 o;
        o.x = (int)pack4(*(const i32x4*)(src + 0));
        o.y = (int)pack4(*(const i32x4*)(src + 4));
        o.z = (int)pack4(*(const i32x4*)(src + 8));
        o.w = (int)pack4(*(const i32x4*)(src + 12));
        *(i32x4*)(ws + WP_OFF + ((size_t)g * N_DIM + n) * 16) = o;
    } else if (t < PXP_N + PWP_N + TSX_N) {
        int i = t - PXP_N - PWP_N;
        int plane = i >> 12;
        int kt = plane >> 1, h = plane & 1;
        int r2 = (i & 4095) << 1;
        int g0 = kt * 4 + h, g2 = g0 + 2;
        int s0 = (g0 < 128) ? g0 : g0 - 128;
        int s2 = (g2 < 128) ? g2 : g2 - 128;
        unsigned b0 = sx[(size_t)r2 * 128 + s0] & 255;
        unsigned b1 = sx[(size_t)r2 * 128 + s2] & 255;
        unsigned b2 = sx[(size_t)(r2 + 1) * 128 + s0] & 255;
        unsigned b3 = sx[(size_t)(r2 + 1) * 128 + s2] & 255;
        *(unsigned*)(ws + SXH_OFF + (size_t)i * 4) = b0 | (b1 << 8) | (b2 << 16) | (b3 << 24);
    } else if (t < PACK_TOTAL) {
        int i = t - PXP_N - PWP_N - TSX_N;
        int plane = i >> 11;
        int kt = plane >> 1, h = plane & 1;
        int r2 = (i & 2047) << 1;
        int g0 = kt * 4 + h, g2 = g0 + 2;
        unsigned b0, b1, b2, b3;
        if (g0 < 128) { b0 = sfw[(size_t)r2 * 128 + g0] & 255; b2 = sfw[(size_t)(r2 + 1) * 128 + g0] & 255; }
        else          { b0 = sflr[(size_t)r2 * 4 + (g0 - 128)] & 255; b2 = sflr[(size_t)(r2 + 1) * 4 + (g0 - 128)] & 255; }
        if (g2 < 128) { b1 = sfw[(size_t)r2 * 128 + g2] & 255; b3 = sfw[(size_t)(r2 + 1) * 128 + g2] & 255; }
        else          { b1 = sflr[(size_t)r2 * 4 + (g2 - 128)] & 255; b3 = sflr[(size_t)(r2 + 1) * 4 + (g2 - 128)] & 255; }
        *(unsigned*)(ws + SWH_OFF + (size_t)i * 4) = b0 | (b1 << 8) | (b2 << 16) | (b3 << 24);
    }
}

__device__ inline void gload_lds16(const void* g, void* l) {
    __builtin_amdgcn_global_load_lds(
        (const __attribute__((address_space(1))) unsigned int*)g,
        (__attribute__((address_space(3))) unsigned int*)l, 16, 0, 0);
}

__device__ inline i32x8 zext8(i32x4 v) {
    return i32x8{v.x, v.y, v.z, v.w, 0, 0, 0, 0};
}

__global__ __launch_bounds__(512, 2)
void l4b_mx6(const uint8_t* __restrict__ xp, const uint8_t* __restrict__ wp,
             const uint8_t* __restrict__ sxH, const uint8_t* __restrict__ swH,
             float* __restrict__ out) {
    // LDS: [dbuf][chunk c=0..3][row 0..255][16B]; A 32KB + B 32KB
    __shared__ __align__(16) uint8_t As[2][4][256][16];
    __shared__ __align__(16) uint8_t Bs[2][4][256][16];

    const int tid = threadIdx.x;
    const int lane = tid & 63;
    const int wid = tid >> 6;
    const int wr = wid >> 2;   // 0..1
    const int wc = wid & 3;    // 0..3

    // XCD-aware bijective swizzle, bn fast axis (A-panels L2-resident per XCD)
    const int bid = blockIdx.x;
    const int wgid = (bid & 7) * 64 + (bid >> 3);
    const int bn = (wgid & 15) * 256;
    const int bm = (wgid >> 4) * 256;

    const int h = lane >> 5, r = lane & 31;

    // ---- loop-carried pointers ----
    const int cst = wid & 3;  // chunk this wave stages
    const uint8_t* ga = (wid < 4)
        ? xp + ((size_t)cst * M_DIM + bm + lane) * 16
        : wp + ((size_t)cst * N_DIM + bn + lane) * 16;
    const size_t gstride = (wid < 4) ? (size_t)4 * M_DIM * 16 : (size_t)4 * N_DIM * 16;
    const uint8_t* psx = sxH + (size_t)(h * M_DIM + bm + wr * 128 + r) * 2;
    const uint8_t* psw = swH + (size_t)(h * N_DIM + bn + wc * 64 + r) * 2;
    // per-lane LDS read base offsets (within one dbuf half)
    const int laneoffA = h * 4096 + (wr * 128 + r) * 16;
    const int laneoffB = h * 4096 + (wc * 64 + r) * 16;

    f32x16 acc[4][2] = {};
    int sa[4], sb[2], san[4], sbn[2];

    // ---- prologue: stage tile 0 into buf 0 ----
    {
        uint8_t(*T)[256][16] = (wid < 4) ? As[0] : Bs[0];
#pragma unroll
        for (int q = 0; q < 4; ++q)
            gload_lds16(ga + q * 1024, &T[cst][q * 64][0]);
        ga += gstride;
    }
#pragma unroll
    for (int mi = 0; mi < 4; ++mi) sa[mi] = *(const unsigned short*)(psx + mi * 64);
#pragma unroll
    for (int ni = 0; ni < 2; ++ni) sb[ni] = *(const unsigned short*)(psw + ni * 64);
    psx += 2 * M_DIM * 2;
    psw += 2 * N_DIM * 2;
    asm volatile("s_waitcnt vmcnt(0)" ::: "memory");
    SBAR();

    int cur = 0;
    for (int t = 0; t < NT; ++t) {
        const int nxt = cur ^ 1;

        // ---- stage tile t+1 (issue early; drained at tile end) ----
        if (t + 1 < NT) {
            uint8_t(*T)[256][16] = (wid < 4) ? As[nxt] : Bs[nxt];
#pragma unroll
            for (int q = 0; q < 4; ++q)
                gload_lds16(ga + q * 1024, &T[cst][q * 64][0]);
            ga += gstride;
#pragma unroll
            for (int mi = 0; mi < 4; ++mi) san[mi] = *(const unsigned short*)(psx + mi * 64);
#pragma unroll
            for (int ni = 0; ni < 2; ++ni) sbn[ni] = *(const unsigned short*)(psw + ni * 64);
            psx += 2 * M_DIM * 2;
            psw += 2 * N_DIM * 2;
        }

        // ---- ds_read 12 frags from buf[cur], base + compile-time offsets ----
        const char* pa = (const char*)As + cur * 16384 + laneoffA;
        const char* pb = (const char*)Bs + cur * 16384 + laneoffB;
        i32x4 af0[4], af1[4], bf0[2], bf1[2];
#pragma unroll
        for (int mi = 0; mi < 4; ++mi) {
            af0[mi] = *(const i32x4*)(pa + mi * 512);
            af1[mi] = *(const i32x4*)(pa + 8192 + mi * 512);
        }
#pragma unroll
        for (int ni = 0; ni < 2; ++ni) {
            bf0[ni] = *(const i32x4*)(pb + ni * 512);
            bf1[ni] = *(const i32x4*)(pb + 8192 + ni * 512);
        }

        // ---- 16-MFMA cluster (kk=0 then kk=1; 8 independent acc chains) ----
        __builtin_amdgcn_s_setprio(1);
        {
            i32x8 a8[4], b8[2];
#pragma unroll
            for (int mi = 0; mi < 4; ++mi) a8[mi] = zext8(af0[mi]);
#pragma unroll
            for (int ni = 0; ni < 2; ++ni) b8[ni] = zext8(bf0[ni]);
#pragma unroll
            for (int mi = 0; mi < 4; ++mi)
#pragma unroll
                for (int ni = 0; ni < 2; ++ni)
                    acc[mi][ni] = __builtin_amdgcn_mfma_scale_f32_32x32x64_f8f6f4(
                        a8[mi], b8[ni], acc[mi][ni], 4, 4, 0, sa[mi], 0, sb[ni]);
        }
        {
            i32x8 a8[4], b8[2];
#pragma unroll
            for (int mi = 0; mi < 4; ++mi) a8[mi] = zext8(af1[mi]);
#pragma unroll
            for (int ni = 0; ni < 2; ++ni) b8[ni] = zext8(bf1[ni]);
#pragma unroll
            for (int mi = 0; mi < 4; ++mi)
#pragma unroll
                for (int ni = 0; ni < 2; ++ni)
                    acc[mi][ni] = __builtin_amdgcn_mfma_scale_f32_32x32x64_f8f6f4(
                        a8[mi], b8[ni], acc[mi][ni], 4, 4, 1, sa[mi], 1, sb[ni]);
        }
        __builtin_amdgcn_s_setprio(0);

        // ---- ONE drain + barrier per tile ----
        asm volatile("s_waitcnt vmcnt(0)" ::: "memory");
        SBAR();

        cur = nxt;
#pragma unroll
        for (int i = 0; i < 4; ++i) sa[i] = san[i];
        sb[0] = sbn[0]; sb[1] = sbn[1];
    }

    // epilogue: 32x32 C/D layout col=lane&31, row=(reg&3)+8*(reg>>2)+4*(lane>>5)
#pragma unroll
    for (int mi = 0; mi < 4; ++mi)
#pragma unroll
        for (int ni = 0; ni < 2; ++ni) {
            const int col = bn + wc * 64 + ni * 32 + (lane & 31);
            const int rb = bm + wr * 128 + mi * 32 + 4 * (lane >> 5);
#pragma unroll
            for (int reg = 0; reg < 16; ++reg) {
                const int row = rb + (reg & 3) + 8 * (reg >> 2);
                out[(size_t)row * N_DIM + col] = acc[mi][ni][reg];
            }
        }
}

// ======================= fallback (fused f16 dequant GEMM) =======================
__device__ inline short8 dequant8_f16(i32x4 q, int sf) {
    unsigned b = (unsigned)q.x | ((unsigned)q.y << 8) |
                 ((unsigned)q.z << 16) | ((unsigned)q.w << 24);
    unsigned me = b & 0x07070707u;
    unsigned mo = (b >> 4) & 0x07070707u;
    const unsigned TLO = 0x3E3C3800u;
    const unsigned THI = 0x46444240u;
    unsigned He = __builtin_amdgcn_perm(THI, TLO, me);
    unsigned Ho = __builtin_amdgcn_perm(THI, TLO, mo);
    He |= (b & 0x08080808u) << 4;
    Ho |= (b & 0x80808080u);
    unsigned d0 = __builtin_amdgcn_perm(He, 0u, 0x05010400u);
    unsigned d1 = __builtin_amdgcn_perm(He, 0u, 0x07000600u);
    unsigned d2 = __builtin_amdgcn_perm(Ho, 0u, 0x05010400u);
    unsigned d3 = __builtin_amdgcn_perm(Ho, 0u, 0x07000600u);
    i32x4 di; di.x = (int)d0; di.y = (int)d1; di.z = (int)d2; di.w = (int)d3;
    half8 hh = __builtin_bit_cast(half8, di);
    unsigned short se = (unsigned short)((sf - 112) << 10);
    int srep = (int)((unsigned)se | ((unsigned)se << 16));
    i32x4 si; si.x = srep; si.y = srep; si.z = srep; si.w = srep;
    hh = hh * __builtin_bit_cast(half8, si);
    return __builtin_bit_cast(short8, hh);
}

__global__ __launch_bounds__(256)
void l4b_fused(const int* __restrict__ x_q, const int* __restrict__ scales_x,
               const int* __restrict__ weight, const int* __restrict__ SF_w,
               const int* __restrict__ lrw, const int* __restrict__ SF_lr,
               float* __restrict__ out) {
    __shared__ short As[128 * 64];
    __shared__ short Bs[128 * 64];
    const int tid = threadIdx.x;
    const int lane = tid & 63;
    const int wid = tid >> 6;
    const int wr = wid >> 1, wc = wid & 1;
    const int bm = blockIdx.y * 128, bn = blockIdx.x * 128;
    const int srow = tid >> 3;
    const int scol = (tid & 7) * 8;
    f32x4 acc[4][4] = {};
    for (int kt = 0; kt < K_TOT / 64; ++kt) {
        const int k0 = kt * 64;
        __syncthreads();
#pragma unroll
        for (int it = 0; it < 4; ++it) {
            const int row = it * 32 + srow;
            const int k = k0 + scol;
            const int ksrc = (k < K_MAIN) ? k : (k - K_MAIN);
            i32x4 q = *(const i32x4*)(x_q + (size_t)(bm + row) * 2048 + (ksrc >> 1));
            int sf = scales_x[(size_t)(bm + row) * 128 + (ksrc >> 5)];
            short8 v = dequant8_f16(q, sf);
            unsigned a = (unsigned)(row * 128 + scol * 2) ^ (unsigned)((row & 7) << 4);
            *(short8*)((char*)As + a) = v;
        }
#pragma unroll
        for (int it = 0; it < 4; ++it) {
            const int row = it * 32 + srow;
            const int k = k0 + scol;
            i32x4 q; int sf;
            if (k < K_MAIN) {
                q = *(const i32x4*)(weight + (size_t)(bn + row) * 2048 + (k >> 1));
                sf = SF_w[(size_t)(bn + row) * 128 + (k >> 5)];
            } else {
                q = *(const i32x4*)(lrw + (size_t)(bn + row) * 64 + ((k - K_MAIN) >> 1));
                sf = SF_lr[(size_t)(bn + row) * 4 + ((k - K_MAIN) >> 5)];
            }
            short8 v = dequant8_f16(q, sf);
            unsigned a = (unsigned)(row * 128 + scol * 2) ^ (unsigned)((row & 7) << 4);
            *(short8*)((char*)Bs + a) = v;
        }
        __syncthreads();
#pragma unroll
        for (int ks = 0; ks < 2; ++ks) {
            const int koff = ks * 32 + (lane >> 4) * 8;
            short8 af[4], bfr[4];
#pragma unroll
            for (int mi = 0; mi < 4; ++mi) {
                const int row = wr * 64 + mi * 16 + (lane & 15);
                unsigned a = (unsigned)(row * 128 + koff * 2) ^ (unsigned)((row & 7) << 4);
                af[mi] = *(const short8*)((const char*)As + a);
            }
#pragma unroll
            for (int ni = 0; ni < 4; ++ni) {
                const int row = wc * 64 + ni * 16 + (lane & 15);
                unsigned a = (unsigned)(row * 128 + koff * 2) ^ (unsigned)((row & 7) << 4);
                bfr[ni] = *(const short8*)((const char*)Bs + a);
            }
#pragma unroll
            for (int mi = 0; mi < 4; ++mi)
#pragma unroll
                for (int ni = 0; ni < 4; ++ni)
                    acc[mi][ni] = __builtin_amdgcn_mfma_f32_16x16x32_f16(
                        __builtin_bit_cast(half8, af[mi]),
                        __builtin_bit_cast(half8, bfr[ni]),
                        acc[mi][ni], 0, 0, 0);
        }
    }
#pragma unroll
    for (int mi = 0; mi < 4; ++mi)
#pragma unroll
        for (int ni = 0; ni < 4; ++ni) {
            const int col = bn + wc * 64 + ni * 16 + (lane & 15);
            const int row0 = bm + wr * 64 + mi * 16 + (lane >> 4) * 4;
#pragma unroll
            for (int r2 = 0; r2 < 4; ++r2)
                out[(size_t)(row0 + r2) * N_DIM + col] = acc[mi][ni][r2];
        }
}

extern "C" void kernel_launch(void* const* d_in, const int* in_sizes, int n_in,
                              void* d_out, int out_size, void* d_ws, size_t ws_size,
                              hipStream_t stream) {
    const int* x_q  = (const int*)d_in[0];
    const int* sx   = (const int*)d_in[1];
    const int* w    = (const int*)d_in[2];
    const int* sfw  = (const int*)d_in[3];
    const int* lrw  = (const int*)d_in[4];
    const int* sflr = (const int*)d_in[5];
    float* out = (float*)d_out;

    if (ws_size >= WS_NEED) {
        uint8_t* ws = (uint8_t*)d_ws;
        pack_kernel<<<(PACK_TOTAL + 255) / 256, 256, 0, stream>>>(x_q, sx, w, sfw, lrw, sflr, ws);
        l4b_mx6<<<(M_DIM / 256) * (N_DIM / 256), 512, 0, stream>>>(
            ws + XP_OFF, ws + WP_OFF, ws + SXH_OFF, ws + SWH_OFF, out);
    } else {
        dim3 grid(N_DIM / 128, M_DIM / 128);
        l4b_fused<<<grid, dim3(256), 0, stream>>>(x_q, sx, w, sfw, lrw, sflr, out);
    }
}